// Round 24
// baseline (105.147 us; speedup 1.0000x reference)
//
#include <hip/hip_runtime.h>
#include <hip/hip_bf16.h>

#define BB 4
#define NN 8192
#define DD 512
#define EE 8
#define OUTD 512
#define TOPM 1024
#define EPSV 1e-6f
#define ITERS 8

using s16x8 = __attribute__((ext_vector_type(8))) short;
using f32x4 = __attribute__((ext_vector_type(4))) float;
typedef unsigned long long u64;

__device__ __forceinline__ unsigned short f2bf(float f) {
  unsigned u = __float_as_uint(f);
  return (unsigned short)((u + 0x7FFFu + ((u >> 16) & 1u)) >> 16);
}

__device__ __forceinline__ void gll16(const void* g, void* l) {
  __builtin_amdgcn_global_load_lds((const __attribute__((address_space(1))) void*)g,
                                   (__attribute__((address_space(3))) void*)l, 16, 0, 0);
}

// ---- gate logits ONLY -> t0 = log(max(x@gw, eps)); init eo/counts ----
// (xbf conversion + expert transpose moved into k_topk's launch: they are
//  needed only by k_gemm and backfill the 224 CUs idle during topk.)
__global__ __launch_bounds__(256) void k_gate(const float* __restrict__ x,
                                              const float* __restrict__ gw,
                                              float* __restrict__ t0,
                                              int* __restrict__ eo,
                                              int* __restrict__ counts) {
  const int tid = threadIdx.x;
  __shared__ float ws[16][4][8];
  if (tid < 16) eo[blockIdx.x * 16 + tid] = -1;                   // 2048*16 = 32768
  if (blockIdx.x == 0 && tid >= 64 && tid < 64 + BB * EE) counts[tid - 64] = 0;
  const int lane = tid & 63;
  const int wq   = tid >> 6;           // wave owns k in [wq*128, wq*128+128)
  const int k2   = wq * 128 + lane * 2;
  const float* gp = gw + (long)k2 * EE;
  const float4 g0 = *(const float4*)(gp);
  const float4 g1 = *(const float4*)(gp + 4);
  const float4 g2 = *(const float4*)(gp + 8);
  const float4 g3 = *(const float4*)(gp + 12);

  const long row0 = (long)blockIdx.x * 16;
  for (int i = 0; i < 16; ++i) {
    const long row = row0 + i;
    const float2 xv = *(const float2*)(x + row * DD + k2);
    float acc[8];
    acc[0] = xv.x * g0.x + xv.y * g2.x;
    acc[1] = xv.x * g0.y + xv.y * g2.y;
    acc[2] = xv.x * g0.z + xv.y * g2.z;
    acc[3] = xv.x * g0.w + xv.y * g2.w;
    acc[4] = xv.x * g1.x + xv.y * g3.x;
    acc[5] = xv.x * g1.y + xv.y * g3.y;
    acc[6] = xv.x * g1.z + xv.y * g3.z;
    acc[7] = xv.x * g1.w + xv.y * g3.w;
    const bool o1 = lane & 1;
    float own, oth, b0, b1, b2, b3, c0, c1, v;
    own = o1 ? acc[1] : acc[0]; oth = o1 ? acc[0] : acc[1];
    b0 = own + __shfl_xor(oth, 1);
    own = o1 ? acc[3] : acc[2]; oth = o1 ? acc[2] : acc[3];
    b1 = own + __shfl_xor(oth, 1);
    own = o1 ? acc[5] : acc[4]; oth = o1 ? acc[4] : acc[5];
    b2 = own + __shfl_xor(oth, 1);
    own = o1 ? acc[7] : acc[6]; oth = o1 ? acc[6] : acc[7];
    b3 = own + __shfl_xor(oth, 1);
    const bool o2 = lane & 2;
    own = o2 ? b1 : b0; oth = o2 ? b0 : b1;
    c0 = own + __shfl_xor(oth, 2);
    own = o2 ? b3 : b2; oth = o2 ? b2 : b3;
    c1 = own + __shfl_xor(oth, 2);
    const bool o4 = lane & 4;
    own = o4 ? c1 : c0; oth = o4 ? c0 : c1;
    v = own + __shfl_xor(oth, 4);
    v += __shfl_xor(v, 8);
    v += __shfl_xor(v, 16);
    v += __shfl_xor(v, 32);
    if (lane < 8) ws[i][wq][lane] = v;   // per-wave k-partial for e=lane
  }
  __syncthreads();
  if (tid < 128) {
    const int row = tid >> 3, e = tid & 7;
    float s = ws[row][0][e] + ws[row][1][e] + ws[row][2][e] + ws[row][3][e];
    t0[row0 * EE + tid] = logf(fmaxf(s, EPSV));   // 512B coalesced store
  }
}

// ---- fused launch: blocks 0..31   = Sinkhorn + exact top-1024 radix select
// ----               blocks 32..2079 = x -> bf16 conversion (for k_gemm)
// ----               blocks 2080..2591 = expert transpose W -> WT (for k_gemm)
// ---- The conversion/transpose blocks fill the 224 CUs idle during topk.
__global__ __attribute__((amdgpu_waves_per_eu(4, 4)))
__launch_bounds__(1024) void k_topk(const float* __restrict__ t0,
                                    float* __restrict__ R,
                                    float* __restrict__ C,
                                    int* __restrict__ expert_of,
                                    const float* __restrict__ x,
                                    unsigned short* __restrict__ xbf,
                                    const float* __restrict__ W,
                                    unsigned short* __restrict__ WT) {
  __shared__ unsigned key[NN];            // 32 KiB (tvm bits / transpose tile)
  __shared__ int hist[4096];              // 16 KiB
  __shared__ int bcast[2];
  __shared__ int wsum[16];
  __shared__ float ws[16][8], Csh[8], Ssh[8];
  const int tid = threadIdx.x;
  if (blockIdx.x >= 32) {
    const int bid = blockIdx.x - 32;
    if (bid < 2048) {
      // ---- xbf conversion: 16 rows/block, 8 floats/thread, coalesced ----
      const long row = (long)bid * 16 + (tid >> 6);
      const int off = (tid & 63) * 8;
      const float* xr = x + row * DD + off;
      const float4 a = *(const float4*)(xr);
      const float4 b4 = *(const float4*)(xr + 4);
      s16x8 xo;
      xo[0] = (short)f2bf(a.x);  xo[1] = (short)f2bf(a.y);
      xo[2] = (short)f2bf(a.z);  xo[3] = (short)f2bf(a.w);
      xo[4] = (short)f2bf(b4.x); xo[5] = (short)f2bf(b4.y);
      xo[6] = (short)f2bf(b4.z); xo[7] = (short)f2bf(b4.w);
      *(s16x8*)(xbf + row * DD + off) = xo;
    } else {
      // ---- expert transpose: f32 [e][k][n] -> bf16 [e][n][k], 64x64 tiles ----
      float (*tl)[65] = (float(*)[65])key;      // reuse key[] LDS (16.6 KiB)
      const int widx = bid - 2048;              // 0..511
      const int e = widx >> 6, rem = widx & 63;
      const int k0 = (rem >> 3) * 64, n0 = (rem & 7) * 64;
      const int ty = tid >> 6, tx = tid & 63;   // ty 0..15
      const float* src = W + ((long)e * DD + k0) * OUTD + n0;
#pragma unroll
      for (int j = 0; j < 4; ++j)
        tl[ty + j * 16][tx] = src[(long)(ty + j * 16) * OUTD + tx];
      __syncthreads();
      unsigned short* dst = WT + ((long)e * OUTD + n0) * DD + k0;
#pragma unroll
      for (int j = 0; j < 4; ++j)
        dst[(long)(ty + j * 16) * DD + tx] = f2bf(tl[tx][ty + j * 16]);
    }
    return;
  }
  const int b = blockIdx.x >> 3, e = blockIdx.x & 7;
  const int wv = tid >> 6, ln = tid & 63;
  const float* tb = t0 + (long)b * NN * EE;

  // ---- Sinkhorn: thread owns rows {j*1024+tid}; E = exp(t0); u = 1/D; v = 1/S ----
  float E[8][8], u[8], dl[8];
#pragma unroll
  for (int j = 0; j < 8; ++j) {
    const float* p = tb + (long)(j * 1024 + tid) * EE;
    float4 a = *(const float4*)p, b4 = *(const float4*)(p + 4);
    E[j][0] = expf(a.x);  E[j][1] = expf(a.y);
    E[j][2] = expf(a.z);  E[j][3] = expf(a.w);
    E[j][4] = expf(b4.x); E[j][5] = expf(b4.y);
    E[j][6] = expf(b4.z); E[j][7] = expf(b4.w);
    key[j * 1024 + tid] = __float_as_uint(p[e]);   // park own-expert t0 in LDS
    u[j] = 1.f;
  }
#pragma unroll
  for (int j = 0; j < 8; ++j)
#pragma unroll
    for (int e2 = 0; e2 < 8; ++e2)
      asm volatile("" : "+v"(E[j][e2]));           // keep-alive (best effort)
  for (int it = 0; it < ITERS; ++it) {
    float P[8] = {0.f,0.f,0.f,0.f,0.f,0.f,0.f,0.f};
#pragma unroll
    for (int j = 0; j < 8; ++j)
#pragma unroll
      for (int e2 = 0; e2 < 8; ++e2) P[e2] += E[j][e2] * u[j];
#pragma unroll
    for (int d = 1; d <= 4; d <<= 1) {
#pragma unroll
      for (int e2 = 0; e2 < 8; ++e2) {
        float tmp = __shfl_xor(P[e2], d);
        P[e2] += ((ln & d) == (e2 & d)) ? tmp : 0.f;
      }
    }
    float pv = P[0];
#pragma unroll
    for (int e2 = 1; e2 < 8; ++e2) pv = ((ln & 7) == e2) ? P[e2] : pv;
#pragma unroll
    for (int d = 8; d < 64; d <<= 1) pv += __shfl_xor(pv, d);
    if (ln < 8) ws[wv][ln] = pv;
    __syncthreads();
    if (tid < 64) {
      const int q = ln >> 3, e2 = ln & 7;
      float s = ws[q][e2] + ws[q + 8][e2];
#pragma unroll
      for (int d = 8; d < 64; d <<= 1) s += __shfl_xor(s, d);
      if (ln < 8) { Csh[ln] = 1.f / s; Ssh[ln] = s; }
    }
    __syncthreads();
    float vv[8];
#pragma unroll
    for (int e2 = 0; e2 < 8; ++e2) vv[e2] = Csh[e2];
#pragma unroll
    for (int j = 0; j < 8; ++j) {
      float d0 = E[j][0] * vv[0];
#pragma unroll
      for (int e2 = 1; e2 < 8; ++e2) d0 += E[j][e2] * vv[e2];
      dl[j] = d0;
      u[j] = 1.f / d0;
    }
    __syncthreads();   // protect ws/Csh WAR before next iteration's writes
  }
  if (e == 0) {        // one block per batch persists R/C for k_post
#pragma unroll
    for (int j = 0; j < 8; ++j) R[(long)b * NN + j * 1024 + tid] = logf(dl[j]);
    if (tid < 8) C[b * EE + tid] = logf(Ssh[tid]);
  }

  // ---- keys + pass-A 12-bit histogram (tvm from LDS, R register-local) ----
  {
    int4 z4 = make_int4(0, 0, 0, 0);
    *(int4*)&hist[tid * 4] = z4;
  }
  __syncthreads();
#pragma unroll
  for (int j = 0; j < 8; ++j) {
    const int n = j * 1024 + tid;
    float f = __uint_as_float(key[n]) - logf(dl[j]);
    unsigned uk = __float_as_uint(f);
    uk = (uk & 0x80000000u) ? ~uk : (uk | 0x80000000u);   // sortable
    key[n] = uk;
    atomicAdd(&hist[uk >> 20], 1);
  }
  __syncthreads();

  unsigned prefix = 0;
  int k = TOPM;
  for (int pass = 0; pass < 3; ++pass) {
    // ---- suffix-scan of 4096 bins: all 1024 threads, 4 bins each ----
    const int4 h4 = *(const int4*)&hist[tid * 4];
    const int s3 = h4.w, s2 = h4.z + s3, s1 = h4.y + s2, s0 = h4.x + s1;
    int inc = s0;
#pragma unroll
    for (int d = 1; d < 64; d <<= 1) {
      int o = __shfl_down(inc, d);
      if (ln + d < 64) inc += o;
    }
    if (ln == 0) wsum[wv] = inc;        // wave total
    __syncthreads();
    if (tid == 0) {
      int run = 0;
      for (int w2 = 15; w2 >= 0; --w2) { int t2 = wsum[w2]; wsum[w2] = run; run += t2; }
    }
    __syncthreads();
    const int above = wsum[wv] + (inc - s0);  // keys in bins above this thread's 4
    const int c0 = above + s0, c1 = above + s1, c2 = above + s2, c3 = above + s3;
    if (c0 >= k && c1 < k)    { bcast[0] = k - c1;    bcast[1] = tid * 4 + 0; }
    if (c1 >= k && c2 < k)    { bcast[0] = k - c2;    bcast[1] = tid * 4 + 1; }
    if (c2 >= k && c3 < k)    { bcast[0] = k - c3;    bcast[1] = tid * 4 + 2; }
    if (c3 >= k && above < k) { bcast[0] = k - above; bcast[1] = tid * 4 + 3; }
    __syncthreads();
    k = bcast[0];
    const unsigned bin = (unsigned)bcast[1];
    if (pass == 0)      prefix = bin << 20;
    else if (pass == 1) prefix |= bin << 8;
    else                prefix |= bin;
    if (pass == 2) break;
    // ---- rebuild hist for next digit among prefix-matching keys ----
    {
      int4 z4 = make_int4(0, 0, 0, 0);
      *(int4*)&hist[tid * 4] = z4;
    }
    __syncthreads();
    if (pass == 0) {
      const unsigned pa = prefix >> 20;
      for (int n = tid; n < NN; n += 1024) {
        unsigned uk = key[n];
        if ((uk >> 20) == pa) atomicAdd(&hist[(uk >> 8) & 4095], 1);
      }
    } else {
      const unsigned pb = prefix >> 8;
      for (int n = tid; n < NN; n += 1024) {
        unsigned uk = key[n];
        if ((uk >> 8) == pb) atomicAdd(&hist[uk & 255], 1);
      }
    }
    __syncthreads();
  }
  const unsigned theta = prefix;
  const int need = k;                  // ties (==theta) to take, lowest index first
  const int base = tid * 8;            // contiguous chunks -> deterministic index order
  int c = 0;
#pragma unroll
  for (int j = 0; j < 8; ++j) if (key[base + j] == theta) ++c;
  int inc2 = c;
#pragma unroll
  for (int d = 1; d < 64; d <<= 1) {
    int o = __shfl_up(inc2, d);
    if (ln >= d) inc2 += o;
  }
  if (ln == 63) wsum[wv] = inc2;
  __syncthreads();
  if (tid == 0) {
    int runv = 0;
    for (int i = 0; i < 16; ++i) { int t2 = wsum[i]; wsum[i] = runv; runv += t2; }
  }
  __syncthreads();
  int run = wsum[wv] + inc2 - c;       // exclusive prefix of this thread's ties
  int* eo = expert_of + b * NN;
  for (int j = 0; j < 8; ++j) {
    int n = base + j;
    unsigned uk = key[n];
    bool sel = false;
    if (uk > theta) sel = true;
    else if (uk == theta) { if (run < need) sel = true; ++run; }
    if (sel) atomicMax(&eo[n], e);     // np scatter: largest expert index wins
  }
}

// ---- compact per-(b,e) token lists + gate values (list-build only; 128 blocks) ----
__global__ __launch_bounds__(256) void k_post(const int* __restrict__ expert_of,
                                              const float* __restrict__ t0,
                                              const float* __restrict__ R,
                                              const float* __restrict__ C,
                                              int* __restrict__ counts,
                                              int* __restrict__ lists,
                                              float* __restrict__ gvals) {
  __shared__ int hist8[8], base8[8];
  const int tid = threadIdx.x;
  if (tid < 8) hist8[tid] = 0;
  __syncthreads();
  const long i = (long)blockIdx.x * 256 + tid;     // block within one batch
  const int b = (int)(i >> 13);
  const int e = expert_of[i];
  int lpos = -1;
  if (e >= 0) lpos = atomicAdd(&hist8[e], 1);      // LDS atomic: ns-scale
  __syncthreads();
  if (tid < 8 && hist8[tid] > 0)
    base8[tid] = atomicAdd(&counts[b * EE + tid], hist8[tid]);  // 1 RMW per (block,e)
  __syncthreads();
  if (e >= 0) {
    const int n = (int)(i & (NN - 1));
    const int be = b * EE + e;
    const int slot = be * TOPM + base8[e] + lpos;
    lists[slot] = n;
    gvals[slot] = expf(t0[i * EE + e] - C[be] - R[i]);
  }
}

// ---- gathered bf16 MFMA GEMM v2 (blocks 0..1023) + zero unselected rows (1024+) ----
__global__ __launch_bounds__(256) void k_gemm(const unsigned short* __restrict__ xbf,
                                              const unsigned short* __restrict__ WT,
                                              const int* __restrict__ counts,
                                              const int* __restrict__ lists,
                                              const float* __restrict__ gvals,
                                              const int* __restrict__ eo,
                                              float* __restrict__ out) {
  const int tid = threadIdx.x;
  if (blockIdx.x >= 1024) {
    // zero output rows of unselected tokens (backfills CUs behind gemm tiles)
    const int row = (blockIdx.x - 1024) * 4 + (tid >> 6);
    if (eo[row] >= 0) return;
    const int ln = tid & 63;
    float4 z = make_float4(0.f, 0.f, 0.f, 0.f);
    float4* p = (float4*)(out + (long)row * OUTD) + ln;
    p[0] = z; p[64] = z;
    return;
  }
  const int id = blockIdx.x;                 // 1024 = xq*256 + be*8 + yq
  const int xq = id >> 8;                    // 0..3  col tile (A-sharing -> same XCD)
  const int be = (id >> 3) & 31;             // b*8+e
  const int yq = id & 7;                     // 0..7  row tile
  const int b = be >> 3, e = be & 7;
  const int cnt = counts[be];
  const int r0 = yq * 128;
  if (r0 >= cnt) return;
  const int c0 = xq * 128;

  __shared__ unsigned short As[128 * 64];    // 16 KiB
  __shared__ unsigned short Bs[128 * 64];    // 16 KiB
  __shared__ int   rowTok[128];
  __shared__ float rowG[128];

  if (tid < 128) {
    int r = r0 + tid;
    rowTok[tid] = (r < cnt) ? lists[be * TOPM + r] : -1;
    rowG[tid]   = (r < cnt) ? gvals[be * TOPM + r] : 0.f;
  }
  __syncthreads();

  const int w = tid >> 6, l = tid & 63;
  const int rbase = w * 32 + (l >> 3);
  const int sL = l & 7;
  const unsigned short* xb_b = xbf + (long)b * NN * DD;
  const unsigned short* wt_e = WT + (long)e * OUTD * DD;
  int tokc[4]; int sGa[4];
#pragma unroll
  for (int c = 0; c < 4; ++c) {
    int r = rbase + c * 8;
    int tk = rowTok[r]; if (tk < 0) tk = 0;
    tokc[c] = tk;
    sGa[c] = (sL ^ (r & 7)) * 8;             // pre-swizzled global k-slot (elems)
  }

  const int wr = w >> 1, wc = w & 1;
  const int fr = l & 15, fq = l >> 4;
  int aoff[4][2], boff[4][2];
#pragma unroll
  for (int m = 0; m < 4; ++m) {
#pragma unroll
    for (int kk = 0; kk < 2; ++kk) {
      int row = wr * 64 + m * 16 + fr;
      aoff[m][kk] = row * 64 + (((fq + 4 * kk) ^ (row & 7)) * 8);
      int col = wc * 64 + m * 16 + fr;
      boff[m][kk] = col * 64 + (((fq + 4 * kk) ^ (col & 7)) * 8);
    }
  }

  f32x4 acc[4][4] = {};

#define STAGE(kb) {                                                          \
    int ko = (kb) * 64;                                                      \
    _Pragma("unroll")                                                        \
    for (int c = 0; c < 4; ++c) {                                            \
      int r = rbase + c * 8;                                                 \
      gll16(xb_b + (long)tokc[c] * DD + ko + sGa[c],                         \
            As + (w * 32 + c * 8) * 64);                                     \
      gll16(wt_e + (long)(c0 + r) * DD + ko + sGa[c],                        \
            Bs + (w * 32 + c * 8) * 64);                                     \
    }                                                                        \
  }

  STAGE(0);
  for (int kb = 0; kb < 8; ++kb) {
    __syncthreads();
    s16x8 af[4][2], bf_[4][2];
#pragma unroll
    for (int m = 0; m < 4; ++m) {
      af[m][0] = *(const s16x8*)(As + aoff[m][0]);
      af[m][1] = *(const s16x8*)(As + aoff[m][1]);
      bf_[m][0] = *(const s16x8*)(Bs + boff[m][0]);
      bf_[m][1] = *(const s16x8*)(Bs + boff[m][1]);
    }
    __syncthreads();
    if (kb < 7) STAGE(kb + 1);
#pragma unroll
    for (int kk = 0; kk < 2; ++kk)
#pragma unroll
      for (int m = 0; m < 4; ++m)
#pragma unroll
        for (int n = 0; n < 4; ++n)
          acc[m][n] = __builtin_amdgcn_mfma_f32_16x16x32_bf16(af[m][kk], bf_[n][kk], acc[m][n], 0, 0, 0);
  }
#undef STAGE

  // epilogue: C/D layout col=lane&15, row=(lane>>4)*4+reg
#pragma unroll
  for (int m = 0; m < 4; ++m) {
    int rbase2 = wr * 64 + m * 16 + fq * 4;
    int tok[4]; float g[4];
#pragma unroll
    for (int j = 0; j < 4; ++j) { tok[j] = rowTok[rbase2 + j]; g[j] = rowG[rbase2 + j]; }
#pragma unroll
    for (int n = 0; n < 4; ++n) {
      int col = c0 + wc * 64 + n * 16 + fr;
#pragma unroll
      for (int j = 0; j < 4; ++j) {
        if (tok[j] >= 0)
          out[((long)b * NN + tok[j]) * OUTD + col] = acc[m][n][j] * g[j];
      }
    }
  }
}

extern "C" void kernel_launch(void* const* d_in, const int* in_sizes, int n_in,
                              void* d_out, int out_size, void* d_ws, size_t ws_size,
                              hipStream_t stream) {
  const float* x  = (const float*)d_in[0];
  const float* gw = (const float*)d_in[1];
  const float* ex = (const float*)d_in[2];
  float* out = (float*)d_out;

  char* wsb = (char*)d_ws;
  float*          t0     = (float*)(wsb);                          // 1 MiB
  unsigned short* xbf    = (unsigned short*)(wsb + (1l << 20));    // 32 MiB
  unsigned short* WT     = (unsigned short*)(wsb + (33l << 20));   // 4 MiB
  const long base = 37l << 20;
  float*          R      = (float*)(wsb + base);                           // 128 KiB
  int*            eo     = (int*)  (wsb + base + (128l << 10));            // 128 KiB
  int*            lists  = (int*)  (wsb + base + (256l << 10));            // 128 KiB
  float*          gvals  = (float*)(wsb + base + (384l << 10));            // 128 KiB
  float*          C      = (float*)(wsb + base + (512l << 10));            // 32 B
  int*            counts = (int*)  (wsb + base + (512l << 10) + 1024);     // 128 B

  k_gate<<<2048, 256, 0, stream>>>(x, gw, t0, eo, counts);
  k_topk<<<32 + 2048 + 512, 1024, 0, stream>>>(t0, R, C, eo, x, xbf, ex, WT);
  k_post<<<128, 256, 0, stream>>>(eo, t0, R, C, counts, lists, gvals);
  k_gemm<<<1024 + (BB * NN) / 4, 256, 0, stream>>>(xbf, WT, counts, lists, gvals, eo, out);
}

// Round 25
// 101.070 us; speedup vs baseline: 1.0403x; 1.0403x over previous
//
#include <hip/hip_runtime.h>
#include <hip/hip_bf16.h>

#define BB 4
#define NN 8192
#define DD 512
#define EE 8
#define OUTD 512
#define TOPM 1024
#define EPSV 1e-6f
#define ITERS 8

using s16x8 = __attribute__((ext_vector_type(8))) short;
using f32x4 = __attribute__((ext_vector_type(4))) float;
typedef unsigned long long u64;

__device__ __forceinline__ unsigned short f2bf(float f) {
  unsigned u = __float_as_uint(f);
  return (unsigned short)((u + 0x7FFFu + ((u >> 16) & 1u)) >> 16);
}

__device__ __forceinline__ void gll16(const void* g, void* l) {
  __builtin_amdgcn_global_load_lds((const __attribute__((address_space(1))) void*)g,
                                   (__attribute__((address_space(3))) void*)l, 16, 0, 0);
}

// ---- gate logits -> t0 = log(max(x@gw, eps)); x -> bf16; expert transpose ----
// k-split across the 4 waves: each lane owns 2 k's -> only 16 gw floats/lane.
__global__ __launch_bounds__(256) void k_gate(const float* __restrict__ x,
                                              const float* __restrict__ gw,
                                              float* __restrict__ t0,
                                              unsigned short* __restrict__ xbf,
                                              int* __restrict__ eo,
                                              int* __restrict__ counts,
                                              const float* __restrict__ W,
                                              unsigned short* __restrict__ WT) {
  const int tid = threadIdx.x;
  if (blockIdx.x >= 2048) {
    // ---- expert transpose: f32 [e][k][n] -> bf16 [e][n][k], 32x32 tiles ----
    __shared__ float tl[32][33];
    const int widx = blockIdx.x - 2048;          // 0..2047
    const int e = widx >> 8, rem = widx & 255;
    const int k0 = (rem >> 4) * 32, n0 = (rem & 15) * 32;
    const int ty = tid >> 5, tx = tid & 31;
    const float* src = W + ((long)e * DD + k0) * OUTD + n0;
#pragma unroll
    for (int j = 0; j < 4; ++j)
      tl[ty + j * 8][tx] = src[(long)(ty + j * 8) * OUTD + tx];
    __syncthreads();
    unsigned short* dst = WT + ((long)e * OUTD + n0) * DD + k0;
#pragma unroll
    for (int j = 0; j < 4; ++j)
      dst[(long)(ty + j * 8) * DD + tx] = f2bf(tl[tx][ty + j * 8]);
    return;
  }
  __shared__ float ws[16][4][8];
  if (tid < 16) eo[blockIdx.x * 16 + tid] = -1;                   // 2048*16 = 32768
  if (blockIdx.x == 0 && tid >= 64 && tid < 64 + BB * EE) counts[tid - 64] = 0;
  const int lane = tid & 63;
  const int wq   = tid >> 6;           // wave owns k in [wq*128, wq*128+128)
  const int k2   = wq * 128 + lane * 2;
  const float* gp = gw + (long)k2 * EE;
  const float4 g0 = *(const float4*)(gp);
  const float4 g1 = *(const float4*)(gp + 4);
  const float4 g2 = *(const float4*)(gp + 8);
  const float4 g3 = *(const float4*)(gp + 12);

  const long row0 = (long)blockIdx.x * 16;
  for (int i = 0; i < 16; ++i) {
    const long row = row0 + i;
    const float2 xv = *(const float2*)(x + row * DD + k2);
    *(unsigned*)(xbf + row * DD + k2) =
        ((unsigned)f2bf(xv.y) << 16) | (unsigned)f2bf(xv.x);

    float acc[8];
    acc[0] = xv.x * g0.x + xv.y * g2.x;
    acc[1] = xv.x * g0.y + xv.y * g2.y;
    acc[2] = xv.x * g0.z + xv.y * g2.z;
    acc[3] = xv.x * g0.w + xv.y * g2.w;
    acc[4] = xv.x * g1.x + xv.y * g3.x;
    acc[5] = xv.x * g1.y + xv.y * g3.y;
    acc[6] = xv.x * g1.z + xv.y * g3.z;
    acc[7] = xv.x * g1.w + xv.y * g3.w;
    const bool o1 = lane & 1;
    float own, oth, b0, b1, b2, b3, c0, c1, v;
    own = o1 ? acc[1] : acc[0]; oth = o1 ? acc[0] : acc[1];
    b0 = own + __shfl_xor(oth, 1);
    own = o1 ? acc[3] : acc[2]; oth = o1 ? acc[2] : acc[3];
    b1 = own + __shfl_xor(oth, 1);
    own = o1 ? acc[5] : acc[4]; oth = o1 ? acc[4] : acc[5];
    b2 = own + __shfl_xor(oth, 1);
    own = o1 ? acc[7] : acc[6]; oth = o1 ? acc[6] : acc[7];
    b3 = own + __shfl_xor(oth, 1);
    const bool o2 = lane & 2;
    own = o2 ? b1 : b0; oth = o2 ? b0 : b1;
    c0 = own + __shfl_xor(oth, 2);
    own = o2 ? b3 : b2; oth = o2 ? b2 : b3;
    c1 = own + __shfl_xor(oth, 2);
    const bool o4 = lane & 4;
    own = o4 ? c1 : c0; oth = o4 ? c0 : c1;
    v = own + __shfl_xor(oth, 4);
    v += __shfl_xor(v, 8);
    v += __shfl_xor(v, 16);
    v += __shfl_xor(v, 32);
    if (lane < 8) ws[i][wq][lane] = v;   // per-wave k-partial for e=lane
  }
  __syncthreads();
  if (tid < 128) {
    const int row = tid >> 3, e = tid & 7;
    float s = ws[row][0][e] + ws[row][1][e] + ws[row][2][e] + ws[row][3][e];
    t0[row0 * EE + tid] = logf(fmaxf(s, EPSV));   // 512B coalesced store
  }
}

// ---- fused: linear-domain Sinkhorn (redundant per e-block, bit-identical) +
// ---- exact top-1024 radix select, 3 passes of 12/12/8 bits ----
__global__ __attribute__((amdgpu_waves_per_eu(4, 4)))
__launch_bounds__(1024) void k_topk(const float* __restrict__ t0,
                                    float* __restrict__ R,
                                    float* __restrict__ C,
                                    int* __restrict__ expert_of) {
  __shared__ unsigned key[NN];            // 32 KiB (holds tvm bits during Sinkhorn)
  __shared__ int hist[4096];              // 16 KiB
  __shared__ int bcast[2];
  __shared__ int wsum[16];
  __shared__ float ws[16][8], Csh[8], Ssh[8];
  const int b = blockIdx.x >> 3, e = blockIdx.x & 7;
  const int tid = threadIdx.x;
  const int wv = tid >> 6, ln = tid & 63;
  const float* tb = t0 + (long)b * NN * EE;

  // ---- Sinkhorn: thread owns rows {j*1024+tid}; E = exp(t0); u = 1/D; v = 1/S ----
  float E[8][8], u[8], dl[8];
#pragma unroll
  for (int j = 0; j < 8; ++j) {
    const float* p = tb + (long)(j * 1024 + tid) * EE;
    float4 a = *(const float4*)p, b4 = *(const float4*)(p + 4);
    E[j][0] = expf(a.x);  E[j][1] = expf(a.y);
    E[j][2] = expf(a.z);  E[j][3] = expf(a.w);
    E[j][4] = expf(b4.x); E[j][5] = expf(b4.y);
    E[j][6] = expf(b4.z); E[j][7] = expf(b4.w);
    key[j * 1024 + tid] = __float_as_uint(p[e]);   // park own-expert t0 in LDS
    u[j] = 1.f;
  }
#pragma unroll
  for (int j = 0; j < 8; ++j)
#pragma unroll
    for (int e2 = 0; e2 < 8; ++e2)
      asm volatile("" : "+v"(E[j][e2]));           // keep-alive (best effort)
  for (int it = 0; it < ITERS; ++it) {
    float P[8] = {0.f,0.f,0.f,0.f,0.f,0.f,0.f,0.f};
#pragma unroll
    for (int j = 0; j < 8; ++j)
#pragma unroll
      for (int e2 = 0; e2 < 8; ++e2) P[e2] += E[j][e2] * u[j];
#pragma unroll
    for (int d = 1; d <= 4; d <<= 1) {
#pragma unroll
      for (int e2 = 0; e2 < 8; ++e2) {
        float tmp = __shfl_xor(P[e2], d);
        P[e2] += ((ln & d) == (e2 & d)) ? tmp : 0.f;
      }
    }
    float pv = P[0];
#pragma unroll
    for (int e2 = 1; e2 < 8; ++e2) pv = ((ln & 7) == e2) ? P[e2] : pv;
#pragma unroll
    for (int d = 8; d < 64; d <<= 1) pv += __shfl_xor(pv, d);
    if (ln < 8) ws[wv][ln] = pv;
    __syncthreads();
    if (tid < 64) {
      const int q = ln >> 3, e2 = ln & 7;
      float s = ws[q][e2] + ws[q + 8][e2];
#pragma unroll
      for (int d = 8; d < 64; d <<= 1) s += __shfl_xor(s, d);
      if (ln < 8) { Csh[ln] = 1.f / s; Ssh[ln] = s; }
    }
    __syncthreads();
    float vv[8];
#pragma unroll
    for (int e2 = 0; e2 < 8; ++e2) vv[e2] = Csh[e2];
#pragma unroll
    for (int j = 0; j < 8; ++j) {
      float d0 = E[j][0] * vv[0];
#pragma unroll
      for (int e2 = 1; e2 < 8; ++e2) d0 += E[j][e2] * vv[e2];
      dl[j] = d0;
      u[j] = 1.f / d0;
    }
    __syncthreads();   // protect ws/Csh WAR before next iteration's writes
  }
  if (e == 0) {        // one block per batch persists R/C for k_post
#pragma unroll
    for (int j = 0; j < 8; ++j) R[(long)b * NN + j * 1024 + tid] = logf(dl[j]);
    if (tid < 8) C[b * EE + tid] = logf(Ssh[tid]);
  }

  // ---- keys + pass-A 12-bit histogram (tvm from LDS, R register-local) ----
  {
    int4 z4 = make_int4(0, 0, 0, 0);
    *(int4*)&hist[tid * 4] = z4;
  }
  __syncthreads();
#pragma unroll
  for (int j = 0; j < 8; ++j) {
    const int n = j * 1024 + tid;
    float f = __uint_as_float(key[n]) - logf(dl[j]);
    unsigned uk = __float_as_uint(f);
    uk = (uk & 0x80000000u) ? ~uk : (uk | 0x80000000u);   // sortable
    key[n] = uk;
    atomicAdd(&hist[uk >> 20], 1);
  }
  __syncthreads();

  unsigned prefix = 0;
  int k = TOPM;
  for (int pass = 0; pass < 3; ++pass) {
    // ---- suffix-scan of 4096 bins: all 1024 threads, 4 bins each ----
    const int4 h4 = *(const int4*)&hist[tid * 4];
    const int s3 = h4.w, s2 = h4.z + s3, s1 = h4.y + s2, s0 = h4.x + s1;
    int inc = s0;
#pragma unroll
    for (int d = 1; d < 64; d <<= 1) {
      int o = __shfl_down(inc, d);
      if (ln + d < 64) inc += o;
    }
    if (ln == 0) wsum[wv] = inc;        // wave total
    __syncthreads();
    if (tid == 0) {
      int run = 0;
      for (int w2 = 15; w2 >= 0; --w2) { int t2 = wsum[w2]; wsum[w2] = run; run += t2; }
    }
    __syncthreads();
    const int above = wsum[wv] + (inc - s0);  // keys in bins above this thread's 4
    const int c0 = above + s0, c1 = above + s1, c2 = above + s2, c3 = above + s3;
    if (c0 >= k && c1 < k)    { bcast[0] = k - c1;    bcast[1] = tid * 4 + 0; }
    if (c1 >= k && c2 < k)    { bcast[0] = k - c2;    bcast[1] = tid * 4 + 1; }
    if (c2 >= k && c3 < k)    { bcast[0] = k - c3;    bcast[1] = tid * 4 + 2; }
    if (c3 >= k && above < k) { bcast[0] = k - above; bcast[1] = tid * 4 + 3; }
    __syncthreads();
    k = bcast[0];
    const unsigned bin = (unsigned)bcast[1];
    if (pass == 0)      prefix = bin << 20;
    else if (pass == 1) prefix |= bin << 8;
    else                prefix |= bin;
    if (pass == 2) break;
    // ---- rebuild hist for next digit among prefix-matching keys ----
    {
      int4 z4 = make_int4(0, 0, 0, 0);
      *(int4*)&hist[tid * 4] = z4;
    }
    __syncthreads();
    if (pass == 0) {
      const unsigned pa = prefix >> 20;
      for (int n = tid; n < NN; n += 1024) {
        unsigned uk = key[n];
        if ((uk >> 20) == pa) atomicAdd(&hist[(uk >> 8) & 4095], 1);
      }
    } else {
      const unsigned pb = prefix >> 8;
      for (int n = tid; n < NN; n += 1024) {
        unsigned uk = key[n];
        if ((uk >> 8) == pb) atomicAdd(&hist[uk & 255], 1);
      }
    }
    __syncthreads();
  }
  const unsigned theta = prefix;
  const int need = k;                  // ties (==theta) to take, lowest index first
  const int base = tid * 8;            // contiguous chunks -> deterministic index order
  int c = 0;
#pragma unroll
  for (int j = 0; j < 8; ++j) if (key[base + j] == theta) ++c;
  int inc2 = c;
#pragma unroll
  for (int d = 1; d < 64; d <<= 1) {
    int o = __shfl_up(inc2, d);
    if (ln >= d) inc2 += o;
  }
  if (ln == 63) wsum[wv] = inc2;
  __syncthreads();
  if (tid == 0) {
    int runv = 0;
    for (int i = 0; i < 16; ++i) { int t2 = wsum[i]; wsum[i] = runv; runv += t2; }
  }
  __syncthreads();
  int run = wsum[wv] + inc2 - c;       // exclusive prefix of this thread's ties
  int* eo = expert_of + b * NN;
  for (int j = 0; j < 8; ++j) {
    int n = base + j;
    unsigned uk = key[n];
    bool sel = false;
    if (uk > theta) sel = true;
    else if (uk == theta) { if (run < need) sel = true; ++run; }
    if (sel) atomicMax(&eo[n], e);     // np scatter: largest expert index wins
  }
}

// ---- compact per-(b,e) token lists + gate values (list-build only; 128 blocks) ----
__global__ __launch_bounds__(256) void k_post(const int* __restrict__ expert_of,
                                              const float* __restrict__ t0,
                                              const float* __restrict__ R,
                                              const float* __restrict__ C,
                                              int* __restrict__ counts,
                                              int* __restrict__ lists,
                                              float* __restrict__ gvals) {
  __shared__ int hist8[8], base8[8];
  const int tid = threadIdx.x;
  if (tid < 8) hist8[tid] = 0;
  __syncthreads();
  const long i = (long)blockIdx.x * 256 + tid;     // block within one batch
  const int b = (int)(i >> 13);
  const int e = expert_of[i];
  int lpos = -1;
  if (e >= 0) lpos = atomicAdd(&hist8[e], 1);      // LDS atomic: ns-scale
  __syncthreads();
  if (tid < 8 && hist8[tid] > 0)
    base8[tid] = atomicAdd(&counts[b * EE + tid], hist8[tid]);  // 1 RMW per (block,e)
  __syncthreads();
  if (e >= 0) {
    const int n = (int)(i & (NN - 1));
    const int be = b * EE + e;
    const int slot = be * TOPM + base8[e] + lpos;
    lists[slot] = n;
    gvals[slot] = expf(t0[i * EE + e] - C[be] - R[i]);
  }
}

// ---- gathered bf16 MFMA GEMM v2 (blocks 0..1023) + zero unselected rows (1024+) ----
__global__ __launch_bounds__(256) void k_gemm(const unsigned short* __restrict__ xbf,
                                              const unsigned short* __restrict__ WT,
                                              const int* __restrict__ counts,
                                              const int* __restrict__ lists,
                                              const float* __restrict__ gvals,
                                              const int* __restrict__ eo,
                                              float* __restrict__ out) {
  const int tid = threadIdx.x;
  if (blockIdx.x >= 1024) {
    // zero output rows of unselected tokens (backfills CUs behind gemm tiles)
    const int row = (blockIdx.x - 1024) * 4 + (tid >> 6);
    if (eo[row] >= 0) return;
    const int ln = tid & 63;
    float4 z = make_float4(0.f, 0.f, 0.f, 0.f);
    float4* p = (float4*)(out + (long)row * OUTD) + ln;
    p[0] = z; p[64] = z;
    return;
  }
  const int id = blockIdx.x;                 // 1024 = xq*256 + be*8 + yq
  const int xq = id >> 8;                    // 0..3  col tile (A-sharing -> same XCD)
  const int be = (id >> 3) & 31;             // b*8+e
  const int yq = id & 7;                     // 0..7  row tile
  const int b = be >> 3, e = be & 7;
  const int cnt = counts[be];
  const int r0 = yq * 128;
  if (r0 >= cnt) return;
  const int c0 = xq * 128;

  __shared__ unsigned short As[128 * 64];    // 16 KiB
  __shared__ unsigned short Bs[128 * 64];    // 16 KiB
  __shared__ int   rowTok[128];
  __shared__ float rowG[128];

  if (tid < 128) {
    int r = r0 + tid;
    rowTok[tid] = (r < cnt) ? lists[be * TOPM + r] : -1;
    rowG[tid]   = (r < cnt) ? gvals[be * TOPM + r] : 0.f;
  }
  __syncthreads();

  const int w = tid >> 6, l = tid & 63;
  const int rbase = w * 32 + (l >> 3);
  const int sL = l & 7;
  const unsigned short* xb_b = xbf + (long)b * NN * DD;
  const unsigned short* wt_e = WT + (long)e * OUTD * DD;
  int tokc[4]; int sGa[4];
#pragma unroll
  for (int c = 0; c < 4; ++c) {
    int r = rbase + c * 8;
    int tk = rowTok[r]; if (tk < 0) tk = 0;
    tokc[c] = tk;
    sGa[c] = (sL ^ (r & 7)) * 8;             // pre-swizzled global k-slot (elems)
  }

  const int wr = w >> 1, wc = w & 1;
  const int fr = l & 15, fq = l >> 4;
  int aoff[4][2], boff[4][2];
#pragma unroll
  for (int m = 0; m < 4; ++m) {
#pragma unroll
    for (int kk = 0; kk < 2; ++kk) {
      int row = wr * 64 + m * 16 + fr;
      aoff[m][kk] = row * 64 + (((fq + 4 * kk) ^ (row & 7)) * 8);
      int col = wc * 64 + m * 16 + fr;
      boff[m][kk] = col * 64 + (((fq + 4 * kk) ^ (col & 7)) * 8);
    }
  }

  f32x4 acc[4][4] = {};

#define STAGE(kb) {                                                          \
    int ko = (kb) * 64;                                                      \
    _Pragma("unroll")                                                        \
    for (int c = 0; c < 4; ++c) {                                            \
      int r = rbase + c * 8;                                                 \
      gll16(xb_b + (long)tokc[c] * DD + ko + sGa[c],                         \
            As + (w * 32 + c * 8) * 64);                                     \
      gll16(wt_e + (long)(c0 + r) * DD + ko + sGa[c],                        \
            Bs + (w * 32 + c * 8) * 64);                                     \
    }                                                                        \
  }

  STAGE(0);
  for (int kb = 0; kb < 8; ++kb) {
    __syncthreads();
    s16x8 af[4][2], bf_[4][2];
#pragma unroll
    for (int m = 0; m < 4; ++m) {
      af[m][0] = *(const s16x8*)(As + aoff[m][0]);
      af[m][1] = *(const s16x8*)(As + aoff[m][1]);
      bf_[m][0] = *(const s16x8*)(Bs + boff[m][0]);
      bf_[m][1] = *(const s16x8*)(Bs + boff[m][1]);
    }
    __syncthreads();
    if (kb < 7) STAGE(kb + 1);
#pragma unroll
    for (int kk = 0; kk < 2; ++kk)
#pragma unroll
      for (int m = 0; m < 4; ++m)
#pragma unroll
        for (int n = 0; n < 4; ++n)
          acc[m][n] = __builtin_amdgcn_mfma_f32_16x16x32_bf16(af[m][kk], bf_[n][kk], acc[m][n], 0, 0, 0);
  }
#undef STAGE

  // epilogue: C/D layout col=lane&15, row=(lane>>4)*4+reg
#pragma unroll
  for (int m = 0; m < 4; ++m) {
    int rbase2 = wr * 64 + m * 16 + fq * 4;
    int tok[4]; float g[4];
#pragma unroll
    for (int j = 0; j < 4; ++j) { tok[j] = rowTok[rbase2 + j]; g[j] = rowG[rbase2 + j]; }
#pragma unroll
    for (int n = 0; n < 4; ++n) {
      int col = c0 + wc * 64 + n * 16 + fr;
#pragma unroll
      for (int j = 0; j < 4; ++j) {
        if (tok[j] >= 0)
          out[((long)b * NN + tok[j]) * OUTD + col] = acc[m][n][j] * g[j];
      }
    }
  }
}

extern "C" void kernel_launch(void* const* d_in, const int* in_sizes, int n_in,
                              void* d_out, int out_size, void* d_ws, size_t ws_size,
                              hipStream_t stream) {
  const float* x  = (const float*)d_in[0];
  const float* gw = (const float*)d_in[1];
  const float* ex = (const float*)d_in[2];
  float* out = (float*)d_out;

  char* wsb = (char*)d_ws;
  float*          t0     = (float*)(wsb);                          // 1 MiB
  unsigned short* xbf    = (unsigned short*)(wsb + (1l << 20));    // 32 MiB
  unsigned short* WT     = (unsigned short*)(wsb + (33l << 20));   // 4 MiB
  const long base = 37l << 20;
  float*          R      = (float*)(wsb + base);                           // 128 KiB
  int*            eo     = (int*)  (wsb + base + (128l << 10));            // 128 KiB
  int*            lists  = (int*)  (wsb + base + (256l << 10));            // 128 KiB
  float*          gvals  = (float*)(wsb + base + (384l << 10));            // 128 KiB
  float*          C      = (float*)(wsb + base + (512l << 10));            // 32 B
  int*            counts = (int*)  (wsb + base + (512l << 10) + 1024);     // 128 B

  k_gate<<<2048 + 2048, 256, 0, stream>>>(x, gw, t0, xbf, eo, counts, ex, WT);
  k_topk<<<BB * EE, 1024, 0, stream>>>(t0, R, C, eo);
  k_post<<<128, 256, 0, stream>>>(eo, t0, R, C, counts, lists, gvals);
  k_gemm<<<1024 + (BB * NN) / 4, 256, 0, stream>>>(xbf, WT, counts, lists, gvals, eo, out);
}